// Round 9
// baseline (292.347 us; speedup 1.0000x reference)
//
#include <hip/hip_runtime.h>
#include <hip/hip_bf16.h>
#include <cstdint>

#define N_PTS 16384
#define DIM   64
#define BM    128          // rows per block
#define CHUNK 2048         // cols per block (R6/R8 best-measured config)
#define NT    (CHUNK / 64) // 32 col-tiles of 64 per block
#define NPANEL (N_PTS / BM)    // 128
#define NCHUNK (N_PTS / CHUNK) // 8

typedef __attribute__((ext_vector_type(8))) short short8;
typedef __attribute__((ext_vector_type(4))) float f32x4;

// ---- workspace layout (bytes) ----
#define A_BF_OFF  0u
#define B_BF_OFF  ((unsigned)(N_PTS * DIM * 2))                 // 2 MB
#define A2_OFF    ((unsigned)(2u * N_PTS * DIM * 2))            // 4 MB
#define B2_OFF    (A2_OFF + (unsigned)(N_PTS * 4))
#define ROW_OFF   (B2_OFF + (unsigned)(N_PTS * 4))              // [NCHUNK][N_PTS] f32
#define COL_OFF   (ROW_OFF + (unsigned)(NCHUNK * N_PTS * 4))    // [NPANEL][N_PTS] f32
#define PART_OFF  (COL_OFF + (unsigned)(NPANEL * N_PTS * 4))    // [64] f32

__device__ __forceinline__ unsigned f2o(float f) {
    unsigned b = __float_as_uint(f);
    return b ^ (unsigned)((((int)b) >> 31) | 0x80000000);
}
__device__ __forceinline__ float o2f(unsigned u) {
    unsigned b = (u & 0x80000000u) ? (u ^ 0x80000000u) : ~u;
    return __uint_as_float(b);
}
__device__ __forceinline__ unsigned short f2bf(float f) {
    unsigned b = __float_as_uint(f);
    b += 0x7FFFu + ((b >> 16) & 1u);
    return (unsigned short)(b >> 16);
}
__device__ __forceinline__ float min3f(float a, float b, float c) {
    return fminf(fminf(a, b), c);   // clang fuses to v_min3_f32
}

// ---------------- convert + norms + k-group-major transpose ----------------
// X'[kg][16384 rows][8 bf16], kg = k/8.  A side scaled by -2 (exact in bf16).
// R9: 64 rows per block (grid 512, was 2048x16 rows) to amortize launch ramp.
__global__ __launch_bounds__(256) void cd_convert(
    const float* __restrict__ a, const float* __restrict__ b,
    unsigned short* __restrict__ abf, unsigned short* __restrict__ bbf,
    float* __restrict__ a2, float* __restrict__ b2) {
    __shared__ ushort4 T[64][17];   // padded: 2-way max on phase-2 reads (free)
    const int blk = blockIdx.x;                 // 0..511
    const bool isB = blk >= (N_PTS / 64);
    const float* src = isB ? b : a;
    unsigned short* dst = isB ? bbf : abf;
    float* nrm = isB ? b2 : a2;
    const int rb = (blk & (N_PTS / 64 - 1)) * 64;
    const int tid = threadIdx.x;
    const float sc = isB ? 1.0f : -2.0f;

    {
        int rg = tid >> 4, part = tid & 15;
        #pragma unroll
        for (int it = 0; it < 4; ++it) {
            int rowl = it * 16 + rg;
            float4 v = ((const float4*)src)[(size_t)(rb + rowl) * 16 + part];
            float s = v.x * v.x + v.y * v.y + v.z * v.z + v.w * v.w;
            s += __shfl_xor(s, 1, 64);
            s += __shfl_xor(s, 2, 64);
            s += __shfl_xor(s, 4, 64);
            s += __shfl_xor(s, 8, 64);
            if (part == 0) nrm[rb + rowl] = s;
            ushort4 u;
            u.x = f2bf(sc * v.x); u.y = f2bf(sc * v.y);
            u.z = f2bf(sc * v.z); u.w = f2bf(sc * v.w);
            T[rowl][part] = u;
        }
    }
    __syncthreads();
    {
        int kgh = tid >> 4, rl0 = tid & 15;
        int kg = kgh >> 1, half = kgh & 1;
        #pragma unroll
        for (int it = 0; it < 4; ++it) {
            int rl = it * 16 + rl0;
            ((ushort4*)dst)[(size_t)(kg * N_PTS + rb + rl) * 2 + half] = T[rl][kgh];
        }
    }
}

// ---------------- fused GEMM + min epilogue ----------------
// R8-verified loop body (fused mfma+epilogue, fire-and-forget ds atomicMin,
// C-init = a2 fragment, min3 trees, b2 deferred on col path).
// R9 single gemm change: prefetch depth 2 -> 4 named buffers (static indexing,
// NT%4==0).  compute(t) waits on a load issued 3 compute-sections (~600+ cyc)
// earlier, fully covering L2 latency.  VGPR budget ~116 <= 128 keeps
// 4 waves/SIMD.
__global__ __launch_bounds__(256, 3) void cd_gemm(
    const unsigned short* __restrict__ abf, const unsigned short* __restrict__ bbf,
    const float* __restrict__ a2, const float* __restrict__ b2,
    float* __restrict__ ws_row, float* __restrict__ ws_col) {

    __shared__ unsigned colmin[CHUNK];     // 8 KB
    __shared__ unsigned rowmin_s[BM];      // 512 B

    const int tid  = threadIdx.x;
    const int lane = tid & 63;
    const int wid  = tid >> 6;
    const int wm   = wid >> 1;
    const int wn   = wid & 1;
    const int l15  = lane & 15;
    const int l4   = lane >> 4;
    const int cblk = blockIdx.x;
    const int pblk = blockIdx.y;
    const int rowbase = pblk * BM;
    const int colbase = cblk * CHUNK;

    for (int i = tid; i < CHUNK; i += 256) colmin[i] = 0xFFFFFFFFu;
    if (tid < BM) rowmin_s[tid] = 0xFFFFFFFFu;

    // A fragments + a2 fragments direct to registers (k-group-major layout)
    short8 af[2][4];
    #pragma unroll
    for (int ks = 0; ks < 2; ++ks)
        #pragma unroll
        for (int m = 0; m < 4; ++m) {
            int arow = rowbase + wm * 64 + m * 16 + l15;
            af[ks][m] = *(const short8*)(abf + (size_t)((ks * 4 + l4) * N_PTS + arow) * 8);
        }
    f32x4 a2v[4];
    #pragma unroll
    for (int m = 0; m < 4; ++m)
        a2v[m] = *(const f32x4*)(a2 + rowbase + wm * 64 + m * 16 + l4 * 4);

    float rowm[16];
    #pragma unroll
    for (int i = 0; i < 16; ++i) rowm[i] = __builtin_inff();

    __syncthreads();   // colmin init visible before any atomicMin

    auto loadB = [&](int t, short8 (&bf)[2][2], float (&bv)[2]) {
        int col0 = colbase + t * 64 + wn * 32;
        #pragma unroll
        for (int n = 0; n < 2; ++n) {
            int col = col0 + n * 16 + l15;
            #pragma unroll
            for (int ks = 0; ks < 2; ++ks)
                bf[ks][n] = *(const short8*)(bbf + (size_t)((ks * 4 + l4) * N_PTS + col) * 8);
            bv[n] = b2[col];
        }
    };

    // ONE fused section per tile (R2/R8-proven schedule).
    auto compute = [&](int t, const short8 (&bf)[2][2], const float (&bv)[2]) {
        f32x4 acc[4][2];
        #pragma unroll
        for (int m = 0; m < 4; ++m)
            #pragma unroll
            for (int n = 0; n < 2; ++n)
                acc[m][n] = __builtin_amdgcn_mfma_f32_16x16x32_bf16(af[0][m], bf[0][n], a2v[m], 0, 0, 0);
        #pragma unroll
        for (int m = 0; m < 4; ++m)
            #pragma unroll
            for (int n = 0; n < 2; ++n)
                acc[m][n] = __builtin_amdgcn_mfma_f32_16x16x32_bf16(af[1][m], bf[1][n], acc[m][n], 0, 0, 0);

        // col tree on raw acc (b2 deferred to cd_reduce)
        float colt[2] = {__builtin_inff(), __builtin_inff()};
        #pragma unroll
        for (int n = 0; n < 2; ++n)
            #pragma unroll
            for (int m = 0; m < 4; ++m) {
                colt[n] = min3f(colt[n], acc[m][n][0], acc[m][n][1]);
                colt[n] = min3f(colt[n], acc[m][n][2], acc[m][n][3]);
            }
        // row tree on acc + b2
        #pragma unroll
        for (int m = 0; m < 4; ++m)
            #pragma unroll
            for (int r = 0; r < 4; ++r)
                rowm[m * 4 + r] = min3f(rowm[m * 4 + r],
                                        acc[m][0][r] + bv[0],
                                        acc[m][1][r] + bv[1]);
        // col cross-lane: all 64 lanes fire-and-forget ds atomic (no return,
        // no lgkmcnt wait in-loop; l4 groups dup 4-way on the same address)
        #pragma unroll
        for (int n = 0; n < 2; ++n)
            atomicMin(&colmin[t * 64 + wn * 32 + n * 16 + l15], f2o(colt[n]));
    };

    // 4-deep named-buffer rotation (NT = 32, multiple of 4; all guards uniform)
    short8 bf0[2][2], bf1[2][2], bf2t[2][2], bf3[2][2];
    float bv0[2], bv1[2], bv2t[2], bv3[2];
    loadB(0, bf0, bv0);
    loadB(1, bf1, bv1);
    loadB(2, bf2t, bv2t);
    for (int t = 0; t < NT; t += 4) {
        if (t + 3 < NT) loadB(t + 3, bf3, bv3);
        compute(t, bf0, bv0);
        if (t + 4 < NT) loadB(t + 4, bf0, bv0);
        compute(t + 1, bf1, bv1);
        if (t + 5 < NT) loadB(t + 5, bf1, bv1);
        compute(t + 2, bf2t, bv2t);
        if (t + 6 < NT) loadB(t + 6, bf2t, bv2t);
        compute(t + 3, bf3, bv3);
    }

    // row mins: reduce over l15 lanes, combine across wn via LDS (once/block)
    #pragma unroll
    for (int i = 0; i < 16; ++i) {
        float v = rowm[i];
        v = fminf(v, __shfl_xor(v, 1, 64));
        v = fminf(v, __shfl_xor(v, 2, 64));
        v = fminf(v, __shfl_xor(v, 4, 64));
        v = fminf(v, __shfl_xor(v, 8, 64));
        if (l15 == 0)
            atomicMin(&rowmin_s[wm * 64 + (i >> 2) * 16 + l4 * 4 + (i & 3)], f2o(v));
    }
    __syncthreads();

    if (tid < BM)
        ws_row[(size_t)cblk * N_PTS + rowbase + tid] = o2f(rowmin_s[tid]);
    for (int i = tid; i < CHUNK; i += 256)
        ws_col[(size_t)pblk * N_PTS + colbase + i] = o2f(colmin[i]);
}

// ---------------- final reduction ----------------
__global__ __launch_bounds__(256) void cd_reduce(
    const float* __restrict__ ws_row, const float* __restrict__ ws_col,
    const float* __restrict__ b2, float* __restrict__ partial) {
    int i = blockIdx.x * 256 + threadIdx.x;    // 0..16383
    float rm = __builtin_inff(), cm = __builtin_inff();
    #pragma unroll 4
    for (int c = 0; c < NCHUNK; ++c) rm = fminf(rm, ws_row[(size_t)c * N_PTS + i]);
    #pragma unroll 4
    for (int p = 0; p < NPANEL; ++p) cm = fminf(cm, ws_col[(size_t)p * N_PTS + i]);
    float cmf = cm + b2[i];                    // deferred b2 for the col path
    float s = sqrtf(fmaxf(rm, 0.f)) + sqrtf(fmaxf(cmf, 0.f));
    s += __shfl_xor(s, 1, 64);
    s += __shfl_xor(s, 2, 64);
    s += __shfl_xor(s, 4, 64);
    s += __shfl_xor(s, 8, 64);
    s += __shfl_xor(s, 16, 64);
    s += __shfl_xor(s, 32, 64);
    __shared__ float wsum[4];
    if ((threadIdx.x & 63) == 0) wsum[threadIdx.x >> 6] = s;
    __syncthreads();
    if (threadIdx.x == 0)
        partial[blockIdx.x] = wsum[0] + wsum[1] + wsum[2] + wsum[3];
}

__global__ void cd_final(const float* __restrict__ partial, float* __restrict__ out) {
    float s = partial[threadIdx.x];   // 64 entries
    s += __shfl_xor(s, 1, 64);
    s += __shfl_xor(s, 2, 64);
    s += __shfl_xor(s, 4, 64);
    s += __shfl_xor(s, 8, 64);
    s += __shfl_xor(s, 16, 64);
    s += __shfl_xor(s, 32, 64);
    if (threadIdx.x == 0) out[0] = s * (1.0f / (2.0f * N_PTS));
}

extern "C" void kernel_launch(void* const* d_in, const int* in_sizes, int n_in,
                              void* d_out, int out_size, void* d_ws, size_t ws_size,
                              hipStream_t stream) {
    const float* a = (const float*)d_in[0];
    const float* b = (const float*)d_in[1];
    char* ws = (char*)d_ws;
    unsigned short* abf = (unsigned short*)(ws + A_BF_OFF);
    unsigned short* bbf = (unsigned short*)(ws + B_BF_OFF);
    float* a2     = (float*)(ws + A2_OFF);
    float* b2     = (float*)(ws + B2_OFF);
    float* ws_row = (float*)(ws + ROW_OFF);
    float* ws_col = (float*)(ws + COL_OFF);
    float* part   = (float*)(ws + PART_OFF);

    cd_convert<<<dim3(2 * N_PTS / 64), 256, 0, stream>>>(a, b, abf, bbf, a2, b2);
    cd_gemm<<<dim3(NCHUNK, NPANEL), 256, 0, stream>>>(abf, bbf, a2, b2, ws_row, ws_col);
    cd_reduce<<<dim3(N_PTS / 256), 256, 0, stream>>>(ws_row, ws_col, b2, part);
    cd_final<<<1, 64, 0, stream>>>(part, (float*)d_out);
}

// Round 10
// 74.991 us; speedup vs baseline: 3.8984x; 3.8984x over previous
//
#include <hip/hip_runtime.h>
#include <hip/hip_bf16.h>
#include <cstdint>

#define N_PTS 16384
#define DIM   64
#define BM    128          // rows per block
#define CHUNK 2048         // cols per block (R6/R8 best-measured config)
#define NT    (CHUNK / 64) // 32 col-tiles of 64 per block
#define NPANEL (N_PTS / BM)    // 128
#define NCHUNK (N_PTS / CHUNK) // 8

typedef __attribute__((ext_vector_type(8))) short short8;
typedef __attribute__((ext_vector_type(4))) float f32x4;

// ---- workspace layout (bytes) ----
#define A_BF_OFF  0u
#define B_BF_OFF  ((unsigned)(N_PTS * DIM * 2))                 // 2 MB
#define A2_OFF    ((unsigned)(2u * N_PTS * DIM * 2))            // 4 MB
#define B2_OFF    (A2_OFF + (unsigned)(N_PTS * 4))
#define ROW_OFF   (B2_OFF + (unsigned)(N_PTS * 4))              // [NCHUNK][N_PTS] f32
#define COL_OFF   (ROW_OFF + (unsigned)(NCHUNK * N_PTS * 4))    // [NPANEL][N_PTS] f32
#define PART_OFF  (COL_OFF + (unsigned)(NPANEL * N_PTS * 4))    // [64] f32

__device__ __forceinline__ unsigned f2o(float f) {
    unsigned b = __float_as_uint(f);
    return b ^ (unsigned)((((int)b) >> 31) | 0x80000000);
}
__device__ __forceinline__ float o2f(unsigned u) {
    unsigned b = (u & 0x80000000u) ? (u ^ 0x80000000u) : ~u;
    return __uint_as_float(b);
}
__device__ __forceinline__ unsigned short f2bf(float f) {
    unsigned b = __float_as_uint(f);
    b += 0x7FFFu + ((b >> 16) & 1u);
    return (unsigned short)(b >> 16);
}
__device__ __forceinline__ float min3f(float a, float b, float c) {
    return fminf(fminf(a, b), c);   // clang fuses to v_min3_f32
}

// ---------------- convert + norms + k-group-major transpose ----------------
// X'[kg][16384 rows][8 bf16], kg = k/8.  A side scaled by -2 (exact in bf16).
// R10: 64 rows per block (grid 512) to amortize launch ramp (R9's convert,
// isolated from R9's gemm spill).
__global__ __launch_bounds__(256) void cd_convert(
    const float* __restrict__ a, const float* __restrict__ b,
    unsigned short* __restrict__ abf, unsigned short* __restrict__ bbf,
    float* __restrict__ a2, float* __restrict__ b2) {
    __shared__ ushort4 T[64][17];   // padded
    const int blk = blockIdx.x;                 // 0..511
    const bool isB = blk >= (N_PTS / 64);
    const float* src = isB ? b : a;
    unsigned short* dst = isB ? bbf : abf;
    float* nrm = isB ? b2 : a2;
    const int rb = (blk & (N_PTS / 64 - 1)) * 64;
    const int tid = threadIdx.x;
    const float sc = isB ? 1.0f : -2.0f;

    {
        int rg = tid >> 4, part = tid & 15;
        #pragma unroll
        for (int it = 0; it < 4; ++it) {
            int rowl = it * 16 + rg;
            float4 v = ((const float4*)src)[(size_t)(rb + rowl) * 16 + part];
            float s = v.x * v.x + v.y * v.y + v.z * v.z + v.w * v.w;
            s += __shfl_xor(s, 1, 64);
            s += __shfl_xor(s, 2, 64);
            s += __shfl_xor(s, 4, 64);
            s += __shfl_xor(s, 8, 64);
            if (part == 0) nrm[rb + rowl] = s;
            ushort4 u;
            u.x = f2bf(sc * v.x); u.y = f2bf(sc * v.y);
            u.z = f2bf(sc * v.z); u.w = f2bf(sc * v.w);
            T[rowl][part] = u;
        }
    }
    __syncthreads();
    {
        int kgh = tid >> 4, rl0 = tid & 15;
        int kg = kgh >> 1, half = kgh & 1;
        #pragma unroll
        for (int it = 0; it < 4; ++it) {
            int rl = it * 16 + rl0;
            ((ushort4*)dst)[(size_t)(kg * N_PTS + rb + rl) * 2 + half] = T[rl][kgh];
        }
    }
}

// ---------------- fused GEMM + min epilogue ----------------
// EXACT R8 kernel (47.4us verified: fused mfma+epilogue, 2-deep ping-pong,
// fire-and-forget ds atomicMin, C-init = a2 fragment, min3 trees, b2 deferred)
// + ONE change: s_setprio(1)/(0) around the MFMA cluster.  This kernel is
// barrier-free with independently-phased waves -- the regime where setprio
// measured +4-7% (m191), not the lockstep-null regime (m190).
// NOTE: prefetch depth is pinned at 2 -- depth 4 spills to scratch (R9,
// 263us, 709MB scratch writes).  Do not deepen.
__global__ __launch_bounds__(256, 3) void cd_gemm(
    const unsigned short* __restrict__ abf, const unsigned short* __restrict__ bbf,
    const float* __restrict__ a2, const float* __restrict__ b2,
    float* __restrict__ ws_row, float* __restrict__ ws_col) {

    __shared__ unsigned colmin[CHUNK];     // 8 KB
    __shared__ unsigned rowmin_s[BM];      // 512 B

    const int tid  = threadIdx.x;
    const int lane = tid & 63;
    const int wid  = tid >> 6;
    const int wm   = wid >> 1;
    const int wn   = wid & 1;
    const int l15  = lane & 15;
    const int l4   = lane >> 4;
    const int cblk = blockIdx.x;
    const int pblk = blockIdx.y;
    const int rowbase = pblk * BM;
    const int colbase = cblk * CHUNK;

    for (int i = tid; i < CHUNK; i += 256) colmin[i] = 0xFFFFFFFFu;
    if (tid < BM) rowmin_s[tid] = 0xFFFFFFFFu;

    // A fragments + a2 fragments direct to registers (k-group-major layout)
    short8 af[2][4];
    #pragma unroll
    for (int ks = 0; ks < 2; ++ks)
        #pragma unroll
        for (int m = 0; m < 4; ++m) {
            int arow = rowbase + wm * 64 + m * 16 + l15;
            af[ks][m] = *(const short8*)(abf + (size_t)((ks * 4 + l4) * N_PTS + arow) * 8);
        }
    f32x4 a2v[4];
    #pragma unroll
    for (int m = 0; m < 4; ++m)
        a2v[m] = *(const f32x4*)(a2 + rowbase + wm * 64 + m * 16 + l4 * 4);

    float rowm[16];
    #pragma unroll
    for (int i = 0; i < 16; ++i) rowm[i] = __builtin_inff();

    __syncthreads();   // colmin init visible before any atomicMin

    auto loadB = [&](int t, short8 (&bf)[2][2], float (&bv)[2]) {
        int col0 = colbase + t * 64 + wn * 32;
        #pragma unroll
        for (int n = 0; n < 2; ++n) {
            int col = col0 + n * 16 + l15;
            #pragma unroll
            for (int ks = 0; ks < 2; ++ks)
                bf[ks][n] = *(const short8*)(bbf + (size_t)((ks * 4 + l4) * N_PTS + col) * 8);
            bv[n] = b2[col];
        }
    };

    // ONE fused section per tile (R2/R8-proven schedule).
    auto compute = [&](int t, const short8 (&bf)[2][2], const float (&bv)[2]) {
        f32x4 acc[4][2];
        __builtin_amdgcn_s_setprio(1);
        #pragma unroll
        for (int m = 0; m < 4; ++m)
            #pragma unroll
            for (int n = 0; n < 2; ++n)
                acc[m][n] = __builtin_amdgcn_mfma_f32_16x16x32_bf16(af[0][m], bf[0][n], a2v[m], 0, 0, 0);
        #pragma unroll
        for (int m = 0; m < 4; ++m)
            #pragma unroll
            for (int n = 0; n < 2; ++n)
                acc[m][n] = __builtin_amdgcn_mfma_f32_16x16x32_bf16(af[1][m], bf[1][n], acc[m][n], 0, 0, 0);
        __builtin_amdgcn_s_setprio(0);

        // col tree on raw acc (b2 deferred to cd_reduce)
        float colt[2] = {__builtin_inff(), __builtin_inff()};
        #pragma unroll
        for (int n = 0; n < 2; ++n)
            #pragma unroll
            for (int m = 0; m < 4; ++m) {
                colt[n] = min3f(colt[n], acc[m][n][0], acc[m][n][1]);
                colt[n] = min3f(colt[n], acc[m][n][2], acc[m][n][3]);
            }
        // row tree on acc + b2
        #pragma unroll
        for (int m = 0; m < 4; ++m)
            #pragma unroll
            for (int r = 0; r < 4; ++r)
                rowm[m * 4 + r] = min3f(rowm[m * 4 + r],
                                        acc[m][0][r] + bv[0],
                                        acc[m][1][r] + bv[1]);
        // col cross-lane: all 64 lanes fire-and-forget ds atomic (no return,
        // no lgkmcnt wait in-loop; l4 groups dup 4-way on the same address)
        #pragma unroll
        for (int n = 0; n < 2; ++n)
            atomicMin(&colmin[t * 64 + wn * 32 + n * 16 + l15], f2o(colt[n]));
    };

    short8 bfA[2][2], bfB[2][2];
    float bvA[2], bvB[2];
    loadB(0, bfA, bvA);
    for (int t = 0; t < NT; t += 2) {
        loadB(t + 1, bfB, bvB);        // prefetch next while computing current
        compute(t, bfA, bvA);
        if (t + 2 < NT) loadB(t + 2, bfA, bvA);
        compute(t + 1, bfB, bvB);
    }

    // row mins: reduce over l15 lanes, combine across wn via LDS (once/block)
    #pragma unroll
    for (int i = 0; i < 16; ++i) {
        float v = rowm[i];
        v = fminf(v, __shfl_xor(v, 1, 64));
        v = fminf(v, __shfl_xor(v, 2, 64));
        v = fminf(v, __shfl_xor(v, 4, 64));
        v = fminf(v, __shfl_xor(v, 8, 64));
        if (l15 == 0)
            atomicMin(&rowmin_s[wm * 64 + (i >> 2) * 16 + l4 * 4 + (i & 3)], f2o(v));
    }
    __syncthreads();

    if (tid < BM)
        ws_row[(size_t)cblk * N_PTS + rowbase + tid] = o2f(rowmin_s[tid]);
    for (int i = tid; i < CHUNK; i += 256)
        ws_col[(size_t)pblk * N_PTS + colbase + i] = o2f(colmin[i]);
}

// ---------------- final reduction ----------------
__global__ __launch_bounds__(256) void cd_reduce(
    const float* __restrict__ ws_row, const float* __restrict__ ws_col,
    const float* __restrict__ b2, float* __restrict__ partial) {
    int i = blockIdx.x * 256 + threadIdx.x;    // 0..16383
    float rm = __builtin_inff(), cm = __builtin_inff();
    #pragma unroll 4
    for (int c = 0; c < NCHUNK; ++c) rm = fminf(rm, ws_row[(size_t)c * N_PTS + i]);
    #pragma unroll 4
    for (int p = 0; p < NPANEL; ++p) cm = fminf(cm, ws_col[(size_t)p * N_PTS + i]);
    float cmf = cm + b2[i];                    // deferred b2 for the col path
    float s = sqrtf(fmaxf(rm, 0.f)) + sqrtf(fmaxf(cmf, 0.f));
    s += __shfl_xor(s, 1, 64);
    s += __shfl_xor(s, 2, 64);
    s += __shfl_xor(s, 4, 64);
    s += __shfl_xor(s, 8, 64);
    s += __shfl_xor(s, 16, 64);
    s += __shfl_xor(s, 32, 64);
    __shared__ float wsum[4];
    if ((threadIdx.x & 63) == 0) wsum[threadIdx.x >> 6] = s;
    __syncthreads();
    if (threadIdx.x == 0)
        partial[blockIdx.x] = wsum[0] + wsum[1] + wsum[2] + wsum[3];
}

__global__ void cd_final(const float* __restrict__ partial, float* __restrict__ out) {
    float s = partial[threadIdx.x];   // 64 entries
    s += __shfl_xor(s, 1, 64);
    s += __shfl_xor(s, 2, 64);
    s += __shfl_xor(s, 4, 64);
    s += __shfl_xor(s, 8, 64);
    s += __shfl_xor(s, 16, 64);
    s += __shfl_xor(s, 32, 64);
    if (threadIdx.x == 0) out[0] = s * (1.0f / (2.0f * N_PTS));
}

extern "C" void kernel_launch(void* const* d_in, const int* in_sizes, int n_in,
                              void* d_out, int out_size, void* d_ws, size_t ws_size,
                              hipStream_t stream) {
    const float* a = (const float*)d_in[0];
    const float* b = (const float*)d_in[1];
    char* ws = (char*)d_ws;
    unsigned short* abf = (unsigned short*)(ws + A_BF_OFF);
    unsigned short* bbf = (unsigned short*)(ws + B_BF_OFF);
    float* a2     = (float*)(ws + A2_OFF);
    float* b2     = (float*)(ws + B2_OFF);
    float* ws_row = (float*)(ws + ROW_OFF);
    float* ws_col = (float*)(ws + COL_OFF);
    float* part   = (float*)(ws + PART_OFF);

    cd_convert<<<dim3(2 * N_PTS / 64), 256, 0, stream>>>(a, b, abf, bbf, a2, b2);
    cd_gemm<<<dim3(NCHUNK, NPANEL), 256, 0, stream>>>(abf, bbf, a2, b2, ws_row, ws_col);
    cd_reduce<<<dim3(N_PTS / 256), 256, 0, stream>>>(ws_row, ws_col, b2, part);
    cd_final<<<1, 64, 0, stream>>>(part, (float*)d_out);
}

// Round 11
// 60.695 us; speedup vs baseline: 4.8166x; 1.2355x over previous
//
#include <hip/hip_runtime.h>
#include <hip/hip_bf16.h>
#include <cstdint>

#define N_PTS 16384
#define DIM   64
#define BM    128          // rows per block
#define CHUNK 2048         // cols per block (R6/R8 best-measured config)
#define NT    (CHUNK / 64) // 32 col-tiles of 64 per block
#define NPANEL (N_PTS / BM)    // 128
#define NCHUNK (N_PTS / CHUNK) // 8
#define RED_BLKS 256       // R11: cd_reduce grid (was 64 -> BW-starved)
#define IPB  (N_PTS / RED_BLKS) // 64 outputs per reduce block

typedef __attribute__((ext_vector_type(8))) short short8;
typedef __attribute__((ext_vector_type(4))) float f32x4;

// ---- workspace layout (bytes) ----
#define A_BF_OFF  0u
#define B_BF_OFF  ((unsigned)(N_PTS * DIM * 2))                 // 2 MB
#define A2_OFF    ((unsigned)(2u * N_PTS * DIM * 2))            // 4 MB
#define B2_OFF    (A2_OFF + (unsigned)(N_PTS * 4))
#define ROW_OFF   (B2_OFF + (unsigned)(N_PTS * 4))              // [NCHUNK][N_PTS] f32
#define COL_OFF   (ROW_OFF + (unsigned)(NCHUNK * N_PTS * 4))    // [NPANEL][N_PTS] f32
#define PART_OFF  (COL_OFF + (unsigned)(NPANEL * N_PTS * 4))    // [RED_BLKS] f32

__device__ __forceinline__ unsigned f2o(float f) {
    unsigned b = __float_as_uint(f);
    return b ^ (unsigned)((((int)b) >> 31) | 0x80000000);
}
__device__ __forceinline__ float o2f(unsigned u) {
    unsigned b = (u & 0x80000000u) ? (u ^ 0x80000000u) : ~u;
    return __uint_as_float(b);
}
__device__ __forceinline__ unsigned short f2bf(float f) {
    unsigned b = __float_as_uint(f);
    b += 0x7FFFu + ((b >> 16) & 1u);
    return (unsigned short)(b >> 16);
}
__device__ __forceinline__ float min3f(float a, float b, float c) {
    return fminf(fminf(a, b), c);   // clang fuses to v_min3_f32
}

// ---------------- convert + norms + k-group-major transpose ----------------
// (unchanged from R10)
__global__ __launch_bounds__(256) void cd_convert(
    const float* __restrict__ a, const float* __restrict__ b,
    unsigned short* __restrict__ abf, unsigned short* __restrict__ bbf,
    float* __restrict__ a2, float* __restrict__ b2) {
    __shared__ ushort4 T[64][17];   // padded
    const int blk = blockIdx.x;                 // 0..511
    const bool isB = blk >= (N_PTS / 64);
    const float* src = isB ? b : a;
    unsigned short* dst = isB ? bbf : abf;
    float* nrm = isB ? b2 : a2;
    const int rb = (blk & (N_PTS / 64 - 1)) * 64;
    const int tid = threadIdx.x;
    const float sc = isB ? 1.0f : -2.0f;

    {
        int rg = tid >> 4, part = tid & 15;
        #pragma unroll
        for (int it = 0; it < 4; ++it) {
            int rowl = it * 16 + rg;
            float4 v = ((const float4*)src)[(size_t)(rb + rowl) * 16 + part];
            float s = v.x * v.x + v.y * v.y + v.z * v.z + v.w * v.w;
            s += __shfl_xor(s, 1, 64);
            s += __shfl_xor(s, 2, 64);
            s += __shfl_xor(s, 4, 64);
            s += __shfl_xor(s, 8, 64);
            if (part == 0) nrm[rb + rowl] = s;
            ushort4 u;
            u.x = f2bf(sc * v.x); u.y = f2bf(sc * v.y);
            u.z = f2bf(sc * v.z); u.w = f2bf(sc * v.w);
            T[rowl][part] = u;
        }
    }
    __syncthreads();
    {
        int kgh = tid >> 4, rl0 = tid & 15;
        int kg = kgh >> 1, half = kgh & 1;
        #pragma unroll
        for (int it = 0; it < 4; ++it) {
            int rl = it * 16 + rl0;
            ((ushort4*)dst)[(size_t)(kg * N_PTS + rb + rl) * 2 + half] = T[rl][kgh];
        }
    }
}

// ---------------- fused GEMM + min epilogue ----------------
// EXACT R10 kernel (45.8us verified).  Do not touch: 2-deep ping-pong
// (4-deep spills, R9), fused mfma+epilogue (splits regress, R3/R5),
// fire-and-forget ds atomicMin (shfl chain stalls, R8), setprio (+3%, R10).
__global__ __launch_bounds__(256, 3) void cd_gemm(
    const unsigned short* __restrict__ abf, const unsigned short* __restrict__ bbf,
    const float* __restrict__ a2, const float* __restrict__ b2,
    float* __restrict__ ws_row, float* __restrict__ ws_col) {

    __shared__ unsigned colmin[CHUNK];     // 8 KB
    __shared__ unsigned rowmin_s[BM];      // 512 B

    const int tid  = threadIdx.x;
    const int lane = tid & 63;
    const int wid  = tid >> 6;
    const int wm   = wid >> 1;
    const int wn   = wid & 1;
    const int l15  = lane & 15;
    const int l4   = lane >> 4;
    const int cblk = blockIdx.x;
    const int pblk = blockIdx.y;
    const int rowbase = pblk * BM;
    const int colbase = cblk * CHUNK;

    for (int i = tid; i < CHUNK; i += 256) colmin[i] = 0xFFFFFFFFu;
    if (tid < BM) rowmin_s[tid] = 0xFFFFFFFFu;

    short8 af[2][4];
    #pragma unroll
    for (int ks = 0; ks < 2; ++ks)
        #pragma unroll
        for (int m = 0; m < 4; ++m) {
            int arow = rowbase + wm * 64 + m * 16 + l15;
            af[ks][m] = *(const short8*)(abf + (size_t)((ks * 4 + l4) * N_PTS + arow) * 8);
        }
    f32x4 a2v[4];
    #pragma unroll
    for (int m = 0; m < 4; ++m)
        a2v[m] = *(const f32x4*)(a2 + rowbase + wm * 64 + m * 16 + l4 * 4);

    float rowm[16];
    #pragma unroll
    for (int i = 0; i < 16; ++i) rowm[i] = __builtin_inff();

    __syncthreads();   // colmin init visible before any atomicMin

    auto loadB = [&](int t, short8 (&bf)[2][2], float (&bv)[2]) {
        int col0 = colbase + t * 64 + wn * 32;
        #pragma unroll
        for (int n = 0; n < 2; ++n) {
            int col = col0 + n * 16 + l15;
            #pragma unroll
            for (int ks = 0; ks < 2; ++ks)
                bf[ks][n] = *(const short8*)(bbf + (size_t)((ks * 4 + l4) * N_PTS + col) * 8);
            bv[n] = b2[col];
        }
    };

    auto compute = [&](int t, const short8 (&bf)[2][2], const float (&bv)[2]) {
        f32x4 acc[4][2];
        __builtin_amdgcn_s_setprio(1);
        #pragma unroll
        for (int m = 0; m < 4; ++m)
            #pragma unroll
            for (int n = 0; n < 2; ++n)
                acc[m][n] = __builtin_amdgcn_mfma_f32_16x16x32_bf16(af[0][m], bf[0][n], a2v[m], 0, 0, 0);
        #pragma unroll
        for (int m = 0; m < 4; ++m)
            #pragma unroll
            for (int n = 0; n < 2; ++n)
                acc[m][n] = __builtin_amdgcn_mfma_f32_16x16x32_bf16(af[1][m], bf[1][n], acc[m][n], 0, 0, 0);
        __builtin_amdgcn_s_setprio(0);

        float colt[2] = {__builtin_inff(), __builtin_inff()};
        #pragma unroll
        for (int n = 0; n < 2; ++n)
            #pragma unroll
            for (int m = 0; m < 4; ++m) {
                colt[n] = min3f(colt[n], acc[m][n][0], acc[m][n][1]);
                colt[n] = min3f(colt[n], acc[m][n][2], acc[m][n][3]);
            }
        #pragma unroll
        for (int m = 0; m < 4; ++m)
            #pragma unroll
            for (int r = 0; r < 4; ++r)
                rowm[m * 4 + r] = min3f(rowm[m * 4 + r],
                                        acc[m][0][r] + bv[0],
                                        acc[m][1][r] + bv[1]);
        #pragma unroll
        for (int n = 0; n < 2; ++n)
            atomicMin(&colmin[t * 64 + wn * 32 + n * 16 + l15], f2o(colt[n]));
    };

    short8 bfA[2][2], bfB[2][2];
    float bvA[2], bvB[2];
    loadB(0, bfA, bvA);
    for (int t = 0; t < NT; t += 2) {
        loadB(t + 1, bfB, bvB);        // prefetch next while computing current
        compute(t, bfA, bvA);
        if (t + 2 < NT) loadB(t + 2, bfA, bvA);
        compute(t + 1, bfB, bvB);
    }

    #pragma unroll
    for (int i = 0; i < 16; ++i) {
        float v = rowm[i];
        v = fminf(v, __shfl_xor(v, 1, 64));
        v = fminf(v, __shfl_xor(v, 2, 64));
        v = fminf(v, __shfl_xor(v, 4, 64));
        v = fminf(v, __shfl_xor(v, 8, 64));
        if (l15 == 0)
            atomicMin(&rowmin_s[wm * 64 + (i >> 2) * 16 + l4 * 4 + (i & 3)], f2o(v));
    }
    __syncthreads();

    if (tid < BM)
        ws_row[(size_t)cblk * N_PTS + rowbase + tid] = o2f(rowmin_s[tid]);
    for (int i = tid; i < CHUNK; i += 256)
        ws_col[(size_t)pblk * N_PTS + colbase + i] = o2f(colmin[i]);
}

// ---------------- final reduction ----------------
// R11: 256 blocks x 256 threads (was 64 blocks -- BW-starved at 25% of CUs,
// 136 loads/thread).  4 waves per block split the reduction axis: wave s
// covers col-panels [32s,32s+32) and row-chunks [2s,2s+2) for the block's
// 64 outputs; LDS-combine; wave 0 does sqrt+sum -> 1 partial per block.
__global__ __launch_bounds__(256) void cd_reduce(
    const float* __restrict__ ws_row, const float* __restrict__ ws_col,
    const float* __restrict__ b2, float* __restrict__ partial) {
    const int tid = threadIdx.x;
    const int il  = tid & 63;           // output index within block
    const int s   = tid >> 6;           // segment = wave id
    const int i   = blockIdx.x * IPB + il;

    float cm = __builtin_inff(), rm = __builtin_inff();
    #pragma unroll 8
    for (int p = s * (NPANEL / 4); p < (s + 1) * (NPANEL / 4); ++p)
        cm = fminf(cm, ws_col[(size_t)p * N_PTS + i]);
    #pragma unroll
    for (int c = s * (NCHUNK / 4); c < (s + 1) * (NCHUNK / 4); ++c)
        rm = fminf(rm, ws_row[(size_t)c * N_PTS + i]);

    __shared__ float scm[4][64], srm[4][64];
    scm[s][il] = cm;
    srm[s][il] = rm;
    __syncthreads();

    if (s == 0) {
        cm = fminf(fminf(scm[0][il], scm[1][il]), fminf(scm[2][il], scm[3][il]));
        rm = fminf(fminf(srm[0][il], srm[1][il]), fminf(srm[2][il], srm[3][il]));
        float v = sqrtf(fmaxf(rm, 0.f)) + sqrtf(fmaxf(cm + b2[i], 0.f));
        v += __shfl_xor(v, 1, 64);
        v += __shfl_xor(v, 2, 64);
        v += __shfl_xor(v, 4, 64);
        v += __shfl_xor(v, 8, 64);
        v += __shfl_xor(v, 16, 64);
        v += __shfl_xor(v, 32, 64);
        if (il == 0) partial[blockIdx.x] = v;
    }
}

__global__ __launch_bounds__(256) void cd_final(
    const float* __restrict__ partial, float* __restrict__ out) {
    float s = partial[threadIdx.x];     // RED_BLKS = 256 entries
    s += __shfl_xor(s, 1, 64);
    s += __shfl_xor(s, 2, 64);
    s += __shfl_xor(s, 4, 64);
    s += __shfl_xor(s, 8, 64);
    s += __shfl_xor(s, 16, 64);
    s += __shfl_xor(s, 32, 64);
    __shared__ float w[4];
    if ((threadIdx.x & 63) == 0) w[threadIdx.x >> 6] = s;
    __syncthreads();
    if (threadIdx.x == 0)
        out[0] = (w[0] + w[1] + w[2] + w[3]) * (1.0f / (2.0f * N_PTS));
}

extern "C" void kernel_launch(void* const* d_in, const int* in_sizes, int n_in,
                              void* d_out, int out_size, void* d_ws, size_t ws_size,
                              hipStream_t stream) {
    const float* a = (const float*)d_in[0];
    const float* b = (const float*)d_in[1];
    char* ws = (char*)d_ws;
    unsigned short* abf = (unsigned short*)(ws + A_BF_OFF);
    unsigned short* bbf = (unsigned short*)(ws + B_BF_OFF);
    float* a2     = (float*)(ws + A2_OFF);
    float* b2     = (float*)(ws + B2_OFF);
    float* ws_row = (float*)(ws + ROW_OFF);
    float* ws_col = (float*)(ws + COL_OFF);
    float* part   = (float*)(ws + PART_OFF);

    cd_convert<<<dim3(2 * N_PTS / 64), 256, 0, stream>>>(a, b, abf, bbf, a2, b2);
    cd_gemm<<<dim3(NCHUNK, NPANEL), 256, 0, stream>>>(abf, bbf, a2, b2, ws_row, ws_col);
    cd_reduce<<<dim3(RED_BLKS), 256, 0, stream>>>(ws_row, ws_col, b2, part);
    cd_final<<<1, 256, 0, stream>>>(part, (float*)d_out);
}

// Round 12
// 54.980 us; speedup vs baseline: 5.3173x; 1.1039x over previous
//
#include <hip/hip_runtime.h>
#include <hip/hip_bf16.h>
#include <cstdint>

#define N_PTS 16384
#define DIM   64
#define BM    128          // rows per block
#define CHUNK 2048         // cols per block (R6/R8 best-measured config)
#define NT    (CHUNK / 64) // 32 col-tiles of 64 per block
#define NPANEL (N_PTS / BM)    // 128
#define NCHUNK (N_PTS / CHUNK) // 8
#define RED_BLKS 64        // reduce: 64 blocks x 256 threads, 1 output/thread

typedef __attribute__((ext_vector_type(8))) short short8;
typedef __attribute__((ext_vector_type(4))) float f32x4;

// ---- workspace layout (bytes) ----
#define A_BF_OFF  0u
#define B_BF_OFF  ((unsigned)(N_PTS * DIM * 2))                 // 2 MB
#define A2_OFF    ((unsigned)(2u * N_PTS * DIM * 2))            // 4 MB
#define B2_OFF    (A2_OFF + (unsigned)(N_PTS * 4))
#define ROW_OFF   (B2_OFF + (unsigned)(N_PTS * 4))              // [NCHUNK][N_PTS] f32 (512KB)
#define GCOL_OFF  (ROW_OFF + (unsigned)(NCHUNK * N_PTS * 4))    // [N_PTS] u32 (64KB)
#define CNT_OFF   (GCOL_OFF + (unsigned)(N_PTS * 4))            // 1 u32 (padded 256B)
#define PART_OFF  (CNT_OFF + 256u)                              // [RED_BLKS] f32

__device__ __forceinline__ unsigned f2o(float f) {
    unsigned b = __float_as_uint(f);
    return b ^ (unsigned)((((int)b) >> 31) | 0x80000000);
}
__device__ __forceinline__ float o2f(unsigned u) {
    unsigned b = (u & 0x80000000u) ? (u ^ 0x80000000u) : ~u;
    return __uint_as_float(b);
}
__device__ __forceinline__ unsigned short f2bf(float f) {
    unsigned b = __float_as_uint(f);
    b += 0x7FFFu + ((b >> 16) & 1u);
    return (unsigned short)(b >> 16);
}
__device__ __forceinline__ float min3f(float a, float b, float c) {
    return fminf(fminf(a, b), c);   // clang fuses to v_min3_f32
}

// ---------------- convert + norms + k-group-major transpose ----------------
// (R10 body) + R12: init gcol to +inf-ordered and zero the reduce counter.
__global__ __launch_bounds__(256) void cd_convert(
    const float* __restrict__ a, const float* __restrict__ b,
    unsigned short* __restrict__ abf, unsigned short* __restrict__ bbf,
    float* __restrict__ a2, float* __restrict__ b2,
    unsigned* __restrict__ gcol, unsigned* __restrict__ counter) {
    __shared__ ushort4 T[64][17];   // padded
    const int blk = blockIdx.x;                 // 0..511
    const int tid = threadIdx.x;

    // R12 init (stream order makes this visible to cd_gemm/cd_reduce)
    if (blk < (N_PTS / 256)) gcol[blk * 256 + tid] = 0xFFFFFFFFu;   // blocks 0..63
    if (blk == 64 && tid == 0) *counter = 0u;

    const bool isB = blk >= (N_PTS / 64);
    const float* src = isB ? b : a;
    unsigned short* dst = isB ? bbf : abf;
    float* nrm = isB ? b2 : a2;
    const int rb = (blk & (N_PTS / 64 - 1)) * 64;
    const float sc = isB ? 1.0f : -2.0f;

    {
        int rg = tid >> 4, part = tid & 15;
        #pragma unroll
        for (int it = 0; it < 4; ++it) {
            int rowl = it * 16 + rg;
            float4 v = ((const float4*)src)[(size_t)(rb + rowl) * 16 + part];
            float s = v.x * v.x + v.y * v.y + v.z * v.z + v.w * v.w;
            s += __shfl_xor(s, 1, 64);
            s += __shfl_xor(s, 2, 64);
            s += __shfl_xor(s, 4, 64);
            s += __shfl_xor(s, 8, 64);
            if (part == 0) nrm[rb + rowl] = s;
            ushort4 u;
            u.x = f2bf(sc * v.x); u.y = f2bf(sc * v.y);
            u.z = f2bf(sc * v.z); u.w = f2bf(sc * v.w);
            T[rowl][part] = u;
        }
    }
    __syncthreads();
    {
        int kgh = tid >> 4, rl0 = tid & 15;
        int kg = kgh >> 1, half = kgh & 1;
        #pragma unroll
        for (int it = 0; it < 4; ++it) {
            int rl = it * 16 + rl0;
            ((ushort4*)dst)[(size_t)(kg * N_PTS + rb + rl) * 2 + half] = T[rl][kgh];
        }
    }
}

// ---------------- fused GEMM + min epilogue ----------------
// Hot loop EXACT R10 (45.7us verified).  Do not touch: 2-deep ping-pong
// (4-deep spills, R9), fused mfma+epilogue (splits regress, R3/R5),
// fire-and-forget ds atomicMin (shfl chain stalls, R8), setprio (+3%, R10).
// R12 (block END only): ws_col store -> global atomicMin into gcol[16384]
// (order-independent => deterministic; removes 8MB write + 8MB read and the
// L2 pollution it caused in the XCD holding our B-chunk).
__global__ __launch_bounds__(256, 3) void cd_gemm(
    const unsigned short* __restrict__ abf, const unsigned short* __restrict__ bbf,
    const float* __restrict__ a2, const float* __restrict__ b2,
    float* __restrict__ ws_row, unsigned* __restrict__ gcol) {

    __shared__ unsigned colmin[CHUNK];     // 8 KB
    __shared__ unsigned rowmin_s[BM];      // 512 B

    const int tid  = threadIdx.x;
    const int lane = tid & 63;
    const int wid  = tid >> 6;
    const int wm   = wid >> 1;
    const int wn   = wid & 1;
    const int l15  = lane & 15;
    const int l4   = lane >> 4;
    const int cblk = blockIdx.x;
    const int pblk = blockIdx.y;
    const int rowbase = pblk * BM;
    const int colbase = cblk * CHUNK;

    for (int i = tid; i < CHUNK; i += 256) colmin[i] = 0xFFFFFFFFu;
    if (tid < BM) rowmin_s[tid] = 0xFFFFFFFFu;

    short8 af[2][4];
    #pragma unroll
    for (int ks = 0; ks < 2; ++ks)
        #pragma unroll
        for (int m = 0; m < 4; ++m) {
            int arow = rowbase + wm * 64 + m * 16 + l15;
            af[ks][m] = *(const short8*)(abf + (size_t)((ks * 4 + l4) * N_PTS + arow) * 8);
        }
    f32x4 a2v[4];
    #pragma unroll
    for (int m = 0; m < 4; ++m)
        a2v[m] = *(const f32x4*)(a2 + rowbase + wm * 64 + m * 16 + l4 * 4);

    float rowm[16];
    #pragma unroll
    for (int i = 0; i < 16; ++i) rowm[i] = __builtin_inff();

    __syncthreads();   // colmin init visible before any atomicMin

    auto loadB = [&](int t, short8 (&bf)[2][2], float (&bv)[2]) {
        int col0 = colbase + t * 64 + wn * 32;
        #pragma unroll
        for (int n = 0; n < 2; ++n) {
            int col = col0 + n * 16 + l15;
            #pragma unroll
            for (int ks = 0; ks < 2; ++ks)
                bf[ks][n] = *(const short8*)(bbf + (size_t)((ks * 4 + l4) * N_PTS + col) * 8);
            bv[n] = b2[col];
        }
    };

    auto compute = [&](int t, const short8 (&bf)[2][2], const float (&bv)[2]) {
        f32x4 acc[4][2];
        __builtin_amdgcn_s_setprio(1);
        #pragma unroll
        for (int m = 0; m < 4; ++m)
            #pragma unroll
            for (int n = 0; n < 2; ++n)
                acc[m][n] = __builtin_amdgcn_mfma_f32_16x16x32_bf16(af[0][m], bf[0][n], a2v[m], 0, 0, 0);
        #pragma unroll
        for (int m = 0; m < 4; ++m)
            #pragma unroll
            for (int n = 0; n < 2; ++n)
                acc[m][n] = __builtin_amdgcn_mfma_f32_16x16x32_bf16(af[1][m], bf[1][n], acc[m][n], 0, 0, 0);
        __builtin_amdgcn_s_setprio(0);

        float colt[2] = {__builtin_inff(), __builtin_inff()};
        #pragma unroll
        for (int n = 0; n < 2; ++n)
            #pragma unroll
            for (int m = 0; m < 4; ++m) {
                colt[n] = min3f(colt[n], acc[m][n][0], acc[m][n][1]);
                colt[n] = min3f(colt[n], acc[m][n][2], acc[m][n][3]);
            }
        #pragma unroll
        for (int m = 0; m < 4; ++m)
            #pragma unroll
            for (int r = 0; r < 4; ++r)
                rowm[m * 4 + r] = min3f(rowm[m * 4 + r],
                                        acc[m][0][r] + bv[0],
                                        acc[m][1][r] + bv[1]);
        #pragma unroll
        for (int n = 0; n < 2; ++n)
            atomicMin(&colmin[t * 64 + wn * 32 + n * 16 + l15], f2o(colt[n]));
    };

    short8 bfA[2][2], bfB[2][2];
    float bvA[2], bvB[2];
    loadB(0, bfA, bvA);
    for (int t = 0; t < NT; t += 2) {
        loadB(t + 1, bfB, bvB);        // prefetch next while computing current
        compute(t, bfA, bvA);
        if (t + 2 < NT) loadB(t + 2, bfA, bvA);
        compute(t + 1, bfB, bvB);
    }

    #pragma unroll
    for (int i = 0; i < 16; ++i) {
        float v = rowm[i];
        v = fminf(v, __shfl_xor(v, 1, 64));
        v = fminf(v, __shfl_xor(v, 2, 64));
        v = fminf(v, __shfl_xor(v, 4, 64));
        v = fminf(v, __shfl_xor(v, 8, 64));
        if (l15 == 0)
            atomicMin(&rowmin_s[wm * 64 + (i >> 2) * 16 + l4 * 4 + (i & 3)], f2o(v));
    }
    __syncthreads();

    if (tid < BM)
        ws_row[(size_t)cblk * N_PTS + rowbase + tid] = o2f(rowmin_s[tid]);
    // R12: columns go to the global min array (order-independent atomic)
    for (int i = tid; i < CHUNK; i += 256)
        atomicMin(&gcol[colbase + i], colmin[i]);
}

// ---------------- final reduction (fused last-block finish) ----------------
// 64 blocks x 256 threads, 1 output/thread: 8 ws_row loads + gcol + b2.
// Last block (counter pattern) sums the 64 partials in fixed order -> out.
__global__ __launch_bounds__(256) void cd_reduce(
    const float* __restrict__ ws_row, const unsigned* __restrict__ gcol,
    const float* __restrict__ b2, float* __restrict__ partial,
    unsigned* __restrict__ counter, float* __restrict__ out) {
    const int tid = threadIdx.x;
    const int i = blockIdx.x * 256 + tid;      // 0..16383

    float rm = __builtin_inff();
    #pragma unroll
    for (int c = 0; c < NCHUNK; ++c) rm = fminf(rm, ws_row[(size_t)c * N_PTS + i]);
    float cm = o2f(gcol[i]);
    float v = sqrtf(fmaxf(rm, 0.f)) + sqrtf(fmaxf(cm + b2[i], 0.f));
    v += __shfl_xor(v, 1, 64);
    v += __shfl_xor(v, 2, 64);
    v += __shfl_xor(v, 4, 64);
    v += __shfl_xor(v, 8, 64);
    v += __shfl_xor(v, 16, 64);
    v += __shfl_xor(v, 32, 64);

    __shared__ float w[4];
    __shared__ bool lastblk;
    if ((tid & 63) == 0) w[tid >> 6] = v;
    __syncthreads();
    if (tid == 0) {
        partial[blockIdx.x] = w[0] + w[1] + w[2] + w[3];
        __threadfence();                       // release partial
        unsigned ret = atomicAdd(counter, 1u);
        lastblk = (ret == RED_BLKS - 1);
    }
    __syncthreads();
    if (lastblk && tid < 64) {
        __threadfence();                       // acquire all partials
        float s = ((volatile float*)partial)[tid];
        s += __shfl_xor(s, 1, 64);
        s += __shfl_xor(s, 2, 64);
        s += __shfl_xor(s, 4, 64);
        s += __shfl_xor(s, 8, 64);
        s += __shfl_xor(s, 16, 64);
        s += __shfl_xor(s, 32, 64);
        if (tid == 0) out[0] = s * (1.0f / (2.0f * N_PTS));
    }
}

extern "C" void kernel_launch(void* const* d_in, const int* in_sizes, int n_in,
                              void* d_out, int out_size, void* d_ws, size_t ws_size,
                              hipStream_t stream) {
    const float* a = (const float*)d_in[0];
    const float* b = (const float*)d_in[1];
    char* ws = (char*)d_ws;
    unsigned short* abf = (unsigned short*)(ws + A_BF_OFF);
    unsigned short* bbf = (unsigned short*)(ws + B_BF_OFF);
    float* a2      = (float*)(ws + A2_OFF);
    float* b2      = (float*)(ws + B2_OFF);
    float* ws_row  = (float*)(ws + ROW_OFF);
    unsigned* gcol = (unsigned*)(ws + GCOL_OFF);
    unsigned* cnt  = (unsigned*)(ws + CNT_OFF);
    float* part    = (float*)(ws + PART_OFF);

    cd_convert<<<dim3(2 * N_PTS / 64), 256, 0, stream>>>(a, b, abf, bbf, a2, b2, gcol, cnt);
    cd_gemm<<<dim3(NCHUNK, NPANEL), 256, 0, stream>>>(abf, bbf, a2, b2, ws_row, gcol);
    cd_reduce<<<dim3(RED_BLKS), 256, 0, stream>>>(ws_row, gcol, b2, part, cnt, (float*)d_out);
}

// Round 13
// 53.731 us; speedup vs baseline: 5.4410x; 1.0233x over previous
//
#include <hip/hip_runtime.h>
#include <hip/hip_bf16.h>
#include <cstdint>

#define N_PTS 16384
#define DIM   64
#define BM    128          // rows per block
#define CHUNK 2048         // cols per block (R6/R8 best-measured config)
#define NT    (CHUNK / 64) // 32 col-tiles of 64 per block
#define NPANEL (N_PTS / BM)    // 128
#define NCHUNK (N_PTS / CHUNK) // 8
#define RED_BLKS 64        // reduce: 64 blocks x 256 threads, 1 output/thread

typedef __attribute__((ext_vector_type(8))) short short8;
typedef __attribute__((ext_vector_type(4))) float f32x4;

// ---- workspace layout (bytes) ----
#define A_BF_OFF  0u
#define B_BF_OFF  ((unsigned)(N_PTS * DIM * 2))                 // 2 MB
#define A2_OFF    ((unsigned)(2u * N_PTS * DIM * 2))            // 4 MB
#define B2_OFF    (A2_OFF + (unsigned)(N_PTS * 4))
#define ROW_OFF   (B2_OFF + (unsigned)(N_PTS * 4))              // [NCHUNK][N_PTS] f32 (512KB)
#define GCOL_OFF  (ROW_OFF + (unsigned)(NCHUNK * N_PTS * 4))    // [N_PTS] u32 (64KB)
#define CNT_OFF   (GCOL_OFF + (unsigned)(N_PTS * 4))            // 1 u32 (padded 256B)
#define PART_OFF  (CNT_OFF + 256u)                              // [RED_BLKS] f32

__device__ __forceinline__ unsigned f2o(float f) {
    unsigned b = __float_as_uint(f);
    return b ^ (unsigned)((((int)b) >> 31) | 0x80000000);
}
__device__ __forceinline__ float o2f(unsigned u) {
    unsigned b = (u & 0x80000000u) ? (u ^ 0x80000000u) : ~u;
    return __uint_as_float(b);
}
__device__ __forceinline__ unsigned short f2bf(float f) {
    unsigned b = __float_as_uint(f);
    b += 0x7FFFu + ((b >> 16) & 1u);
    return (unsigned short)(b >> 16);
}
__device__ __forceinline__ float min3f(float a, float b, float c) {
    return fminf(fminf(a, b), c);   // clang fuses to v_min3_f32
}

// ---------------- convert + norms + k-group-major transpose ----------------
// (unchanged from R12)
__global__ __launch_bounds__(256) void cd_convert(
    const float* __restrict__ a, const float* __restrict__ b,
    unsigned short* __restrict__ abf, unsigned short* __restrict__ bbf,
    float* __restrict__ a2, float* __restrict__ b2,
    unsigned* __restrict__ gcol, unsigned* __restrict__ counter) {
    __shared__ ushort4 T[64][17];   // padded
    const int blk = blockIdx.x;                 // 0..511
    const int tid = threadIdx.x;

    if (blk < (N_PTS / 256)) gcol[blk * 256 + tid] = 0xFFFFFFFFu;   // blocks 0..63
    if (blk == 64 && tid == 0) *counter = 0u;

    const bool isB = blk >= (N_PTS / 64);
    const float* src = isB ? b : a;
    unsigned short* dst = isB ? bbf : abf;
    float* nrm = isB ? b2 : a2;
    const int rb = (blk & (N_PTS / 64 - 1)) * 64;
    const float sc = isB ? 1.0f : -2.0f;

    {
        int rg = tid >> 4, part = tid & 15;
        #pragma unroll
        for (int it = 0; it < 4; ++it) {
            int rowl = it * 16 + rg;
            float4 v = ((const float4*)src)[(size_t)(rb + rowl) * 16 + part];
            float s = v.x * v.x + v.y * v.y + v.z * v.z + v.w * v.w;
            s += __shfl_xor(s, 1, 64);
            s += __shfl_xor(s, 2, 64);
            s += __shfl_xor(s, 4, 64);
            s += __shfl_xor(s, 8, 64);
            if (part == 0) nrm[rb + rowl] = s;
            ushort4 u;
            u.x = f2bf(sc * v.x); u.y = f2bf(sc * v.y);
            u.z = f2bf(sc * v.z); u.w = f2bf(sc * v.w);
            T[rowl][part] = u;
        }
    }
    __syncthreads();
    {
        int kgh = tid >> 4, rl0 = tid & 15;
        int kg = kgh >> 1, half = kgh & 1;
        #pragma unroll
        for (int it = 0; it < 4; ++it) {
            int rl = it * 16 + rl0;
            ((ushort4*)dst)[(size_t)(kg * N_PTS + rb + rl) * 2 + half] = T[rl][kgh];
        }
    }
}

// ---------------- fused GEMM + min epilogue ----------------
// Same verified schedule as R10/R12 (2-deep ping-pong, fused compute,
// fire-and-forget ds atomicMin, setprio, C-init=a2).  R13: address
// generation replaced by RUNNING POINTERS advanced by per-tile constants
// (B ptrs +1024B, b2 +64 floats, colmin +64 elems; intra-tile deltas are
// immediate offsets), and the row epilogue is vector-typed to invite
// v_pk_add_f32.  Goal: cut ~2.5x VALU addressing overhead (issue-bound).
__global__ __launch_bounds__(256, 3) void cd_gemm(
    const unsigned short* __restrict__ abf, const unsigned short* __restrict__ bbf,
    const float* __restrict__ a2, const float* __restrict__ b2,
    float* __restrict__ ws_row, unsigned* __restrict__ gcol) {

    __shared__ unsigned colmin[CHUNK];     // 8 KB
    __shared__ unsigned rowmin_s[BM];      // 512 B

    const int tid  = threadIdx.x;
    const int lane = tid & 63;
    const int wid  = tid >> 6;
    const int wm   = wid >> 1;
    const int wn   = wid & 1;
    const int l15  = lane & 15;
    const int l4   = lane >> 4;
    const int cblk = blockIdx.x;
    const int pblk = blockIdx.y;
    const int rowbase = pblk * BM;
    const int colbase = cblk * CHUNK;

    for (int i = tid; i < CHUNK; i += 256) colmin[i] = 0xFFFFFFFFu;
    if (tid < BM) rowmin_s[tid] = 0xFFFFFFFFu;

    short8 af[2][4];
    #pragma unroll
    for (int ks = 0; ks < 2; ++ks)
        #pragma unroll
        for (int m = 0; m < 4; ++m) {
            int arow = rowbase + wm * 64 + m * 16 + l15;
            af[ks][m] = *(const short8*)(abf + (size_t)((ks * 4 + l4) * N_PTS + arow) * 8);
        }
    f32x4 a2v[4];
    #pragma unroll
    for (int m = 0; m < 4; ++m)
        a2v[m] = *(const f32x4*)(a2 + rowbase + wm * 64 + m * 16 + l4 * 4);

    f32x4 rowm4[4];
    #pragma unroll
    for (int m = 0; m < 4; ++m)
        rowm4[m] = (f32x4){__builtin_inff(), __builtin_inff(),
                           __builtin_inff(), __builtin_inff()};

    __syncthreads();   // colmin init visible before any atomicMin

    // R13 running pointers (advance by constants; calls are in ascending t)
    const unsigned short* pB0 = bbf + (size_t)(l4 * N_PTS + colbase + wn * 32 + l15) * 8;
    const unsigned short* pB1 = pB0 + (size_t)4 * N_PTS * 8;
    const float* pb2 = b2 + colbase + wn * 32 + l15;
    unsigned coff = wn * 32 + l15;     // colmin element offset, +64/tile

    auto loadB = [&](short8 (&bf)[2][2], float (&bv)[2]) {
        bf[0][0] = *(const short8*)(pB0);
        bf[0][1] = *(const short8*)(pB0 + 128);   // +16 cols = 256B immediate
        bf[1][0] = *(const short8*)(pB1);
        bf[1][1] = *(const short8*)(pB1 + 128);
        bv[0] = pb2[0];
        bv[1] = pb2[16];
        pB0 += 512;  pB1 += 512;  pb2 += 64;      // next 64-col tile
    };

    auto compute = [&](const short8 (&bf)[2][2], const float (&bv)[2]) {
        f32x4 acc[4][2];
        __builtin_amdgcn_s_setprio(1);
        #pragma unroll
        for (int m = 0; m < 4; ++m)
            #pragma unroll
            for (int n = 0; n < 2; ++n)
                acc[m][n] = __builtin_amdgcn_mfma_f32_16x16x32_bf16(af[0][m], bf[0][n], a2v[m], 0, 0, 0);
        #pragma unroll
        for (int m = 0; m < 4; ++m)
            #pragma unroll
            for (int n = 0; n < 2; ++n)
                acc[m][n] = __builtin_amdgcn_mfma_f32_16x16x32_bf16(af[1][m], bf[1][n], acc[m][n], 0, 0, 0);
        __builtin_amdgcn_s_setprio(0);

        // col tree on raw acc (b2 deferred to cd_reduce)
        float colt[2] = {__builtin_inff(), __builtin_inff()};
        #pragma unroll
        for (int n = 0; n < 2; ++n)
            #pragma unroll
            for (int m = 0; m < 4; ++m) {
                colt[n] = min3f(colt[n], acc[m][n][0], acc[m][n][1]);
                colt[n] = min3f(colt[n], acc[m][n][2], acc[m][n][3]);
            }
        // row path: vector adds (v_pk_add_f32 candidates) + vector mins
        #pragma unroll
        for (int m = 0; m < 4; ++m) {
            f32x4 s0 = acc[m][0] + bv[0];
            f32x4 s1 = acc[m][1] + bv[1];
            rowm4[m] = __builtin_elementwise_min(rowm4[m],
                        __builtin_elementwise_min(s0, s1));
        }
        // col cross-lane: fire-and-forget ds atomic at running offset
        atomicMin(&colmin[coff], f2o(colt[0]));
        atomicMin(&colmin[coff + 16], f2o(colt[1]));
        coff += 64;
    };

    short8 bfA[2][2], bfB[2][2];
    float bvA[2], bvB[2];
    loadB(bfA, bvA);
    for (int t = 0; t < NT; t += 2) {
        loadB(bfB, bvB);               // prefetch next while computing current
        compute(bfA, bvA);
        if (t + 2 < NT) loadB(bfA, bvA);
        compute(bfB, bvB);
    }

    // row mins: reduce over l15 lanes, combine across wn via LDS (once/block)
    #pragma unroll
    for (int m = 0; m < 4; ++m)
        #pragma unroll
        for (int r = 0; r < 4; ++r) {
            float v = rowm4[m][r];
            v = fminf(v, __shfl_xor(v, 1, 64));
            v = fminf(v, __shfl_xor(v, 2, 64));
            v = fminf(v, __shfl_xor(v, 4, 64));
            v = fminf(v, __shfl_xor(v, 8, 64));
            if (l15 == 0)
                atomicMin(&rowmin_s[wm * 64 + m * 16 + l4 * 4 + r], f2o(v));
        }
    __syncthreads();

    if (tid < BM)
        ws_row[(size_t)cblk * N_PTS + rowbase + tid] = o2f(rowmin_s[tid]);
    for (int i = tid; i < CHUNK; i += 256)
        atomicMin(&gcol[colbase + i], colmin[i]);
}

// ---------------- final reduction (fused last-block finish) ----------------
// (unchanged from R12)
__global__ __launch_bounds__(256) void cd_reduce(
    const float* __restrict__ ws_row, const unsigned* __restrict__ gcol,
    const float* __restrict__ b2, float* __restrict__ partial,
    unsigned* __restrict__ counter, float* __restrict__ out) {
    const int tid = threadIdx.x;
    const int i = blockIdx.x * 256 + tid;      // 0..16383

    float rm = __builtin_inff();
    #pragma unroll
    for (int c = 0; c < NCHUNK; ++c) rm = fminf(rm, ws_row[(size_t)c * N_PTS + i]);
    float cm = o2f(gcol[i]);
    float v = sqrtf(fmaxf(rm, 0.f)) + sqrtf(fmaxf(cm + b2[i], 0.f));
    v += __shfl_xor(v, 1, 64);
    v += __shfl_xor(v, 2, 64);
    v += __shfl_xor(v, 4, 64);
    v += __shfl_xor(v, 8, 64);
    v += __shfl_xor(v, 16, 64);
    v += __shfl_xor(v, 32, 64);

    __shared__ float w[4];
    __shared__ bool lastblk;
    if ((tid & 63) == 0) w[tid >> 6] = v;
    __syncthreads();
    if (tid == 0) {
        partial[blockIdx.x] = w[0] + w[1] + w[2] + w[3];
        __threadfence();                       // release partial
        unsigned ret = atomicAdd(counter, 1u);
        lastblk = (ret == RED_BLKS - 1);
    }
    __syncthreads();
    if (lastblk && tid < 64) {
        __threadfence();                       // acquire all partials
        float s = ((volatile float*)partial)[tid];
        s += __shfl_xor(s, 1, 64);
        s += __shfl_xor(s, 2, 64);
        s += __shfl_xor(s, 4, 64);
        s += __shfl_xor(s, 8, 64);
        s += __shfl_xor(s, 16, 64);
        s += __shfl_xor(s, 32, 64);
        if (tid == 0) out[0] = s * (1.0f / (2.0f * N_PTS));
    }
}

extern "C" void kernel_launch(void* const* d_in, const int* in_sizes, int n_in,
                              void* d_out, int out_size, void* d_ws, size_t ws_size,
                              hipStream_t stream) {
    const float* a = (const float*)d_in[0];
    const float* b = (const float*)d_in[1];
    char* ws = (char*)d_ws;
    unsigned short* abf = (unsigned short*)(ws + A_BF_OFF);
    unsigned short* bbf = (unsigned short*)(ws + B_BF_OFF);
    float* a2      = (float*)(ws + A2_OFF);
    float* b2      = (float*)(ws + B2_OFF);
    float* ws_row  = (float*)(ws + ROW_OFF);
    unsigned* gcol = (unsigned*)(ws + GCOL_OFF);
    unsigned* cnt  = (unsigned*)(ws + CNT_OFF);
    float* part    = (float*)(ws + PART_OFF);

    cd_convert<<<dim3(2 * N_PTS / 64), 256, 0, stream>>>(a, b, abf, bbf, a2, b2, gcol, cnt);
    cd_gemm<<<dim3(NCHUNK, NPANEL), 256, 0, stream>>>(abf, bbf, a2, b2, ws_row, gcol);
    cd_reduce<<<dim3(RED_BLKS), 256, 0, stream>>>(ws_row, gcol, b2, part, cnt, (float*)d_out);
}